// Round 6
// baseline (4950.214 us; speedup 1.0000x reference)
//
#include <hip/hip_runtime.h>
#include <math.h>

#define EOS_TOK 1
#define SOS_TOK 2
#define Bn 32
#define Hn 512
#define En 256
#define Vn 32000
#define G3H 1536
#define NBLK 256
#define NTHR 1024
#define VPB 125                  // V rows per block (256*125 = 32000 exact)
#define GPB 6                    // gh rows per block (256*6 = 1536 exact)
#define CE 0.0085f               // rigorous bf16 logit error coefficient
#define LCAP 2048                // candidate list; overflow -> full-scan fallback

typedef unsigned long long ull;
typedef unsigned int uint;
typedef __attribute__((ext_vector_type(8))) __bf16 bf16x8;
typedef __attribute__((ext_vector_type(4))) float f32x4;

union U4B { uint4 u; bf16x8 b; };
__device__ __forceinline__ bf16x8 u2b(uint4 u) { U4B x; x.u = u; return x.b; }

// ---- workspace layout (bytes) ----
#define WBF_OFF 0ull             // bf16 W_proj [32000][512]  (32,768,000)
#define WN_OFF  32768000ull      // row norms float[32000]
#define GH_OFF  32896000ull      // gh fp32 [32][1536]
#define ES_OFF  33092608ull      // exact slots [2][8][32] ull
#define LBS_OFF 33096704ull      // lb slots    [2][8][32] ull
#define DN_OFF  33100800ull      // done [2][32] int
#define H_OFF   33101056ull      // h fp32 [32][512]
#define HBF_OFF 33166592ull      // h bf16 [32][512] ushort (32 KB)

struct WS {
    unsigned short* wbf; float* wn; float* gh; ull* es; ull* lbs; int* done; float* h;
    unsigned short* hbf;
};
__device__ __forceinline__ WS get_ws(void* p) {
    WS w;
    w.wbf = (unsigned short*)((char*)p + WBF_OFF);
    w.wn  = (float*)((char*)p + WN_OFF);
    w.gh  = (float*)((char*)p + GH_OFF);
    w.es  = (ull*)((char*)p + ES_OFF);
    w.lbs = (ull*)((char*)p + LBS_OFF);
    w.done= (int*)((char*)p + DN_OFF);
    w.h   = (float*)((char*)p + H_OFF);
    w.hbf = (unsigned short*)((char*)p + HBF_OFF);
    return w;
}

// ---- relaxed agent-scope accessors ----
template <typename T>
__device__ __forceinline__ T ldA(const T* p) {
    return __hip_atomic_load(p, __ATOMIC_RELAXED, __HIP_MEMORY_SCOPE_AGENT);
}
template <typename T>
__device__ __forceinline__ void stA(T* p, T v) {
    __hip_atomic_store(p, v, __ATOMIC_RELAXED, __HIP_MEMORY_SCOPE_AGENT);
}

// ---- fence-free grid barrier (proven R4+) ----
struct PadCnt { ull v; ull pad[7]; };
__device__ PadCnt g_leaf[32];
__device__ ull    g_release;

__device__ __forceinline__ void grid_barrier(int bid) {
    __syncthreads();
    if (threadIdx.x == 0) {
        __builtin_amdgcn_s_waitcnt(0);
        ull my = __hip_atomic_fetch_add(&g_leaf[bid >> 3].v, 1ull,
                                        __ATOMIC_RELAXED, __HIP_MEMORY_SCOPE_AGENT) + 1;
        ull k = (my + 7) >> 3;
        if (bid == 0) {
            ull need = k << 3;
            for (;;) {
                bool again = false;
                #pragma unroll
                for (int i = 0; i < 32; ++i) again |= (ldA(&g_leaf[i].v) < need);
                if (!again) break;
                __builtin_amdgcn_s_sleep(1);
            }
            stA(&g_release, k);
        } else {
            while (ldA(&g_release) < k) __builtin_amdgcn_s_sleep(2);
        }
        __asm__ __volatile__("" ::: "memory");
    }
    __syncthreads();
}

// ---- helpers ----
__device__ __forceinline__ uint fkey(float f) {
    uint b = __float_as_uint(f);
    return (b & 0x80000000u) ? ~b : (b | 0x80000000u);
}
__device__ __forceinline__ float ifkey(uint k) {
    uint b = (k & 0x80000000u) ? (k ^ 0x80000000u) : ~k;
    return __uint_as_float(b);
}
__device__ __forceinline__ uint f2bf(float f) {      // RN fp32->bf16
    uint u = __float_as_uint(f);
    return (u + 0x7FFFu + ((u >> 16) & 1u)) >> 16;
}
__device__ __forceinline__ float bflo(uint u) { return __uint_as_float(u << 16); }
__device__ __forceinline__ float bfhi(uint u) { return __uint_as_float(u & 0xFFFF0000u); }
__device__ __forceinline__ float ulo(ull u) { return __uint_as_float((uint)u); }
__device__ __forceinline__ float uhi(ull u) { return __uint_as_float((uint)(u >> 32)); }

// ---- LDS (~53 KB) ----
struct SM {
    uint4 h4[2048];              // 32 KB bf16 h-hat, [b][e8 ^ b]
    float hn[32];                // CE * ||h-hat||
    float lbv[32];               // own-block lower bound (selection)
    float lbv2[32];              // fresh global lower bound (refilter)
    float ghsc[GPB * 32 * 6];    // gh partials [r6][b][ks]
    ull   red[256];              // 8 waves x 32 batch lb keys
    int   cnt; int pad0[3];
    unsigned short sidx[LCAP];   // candidate (rl<<5)|b  (4 KB)
    float sU[LCAP];              // candidate upper bound (8 KB)
    int   tok[32];
    float gx[192];               // [ci][gate][b]
};

// ---- prologue: h init (fp32 + bf16) + W bf16 conversion + row norms ----
__device__ void prologue(int tid, int bid, const float* __restrict__ hidden,
                         const float* __restrict__ W_proj, WS w)
{
    for (int i = bid * NTHR + tid; i < Bn * Hn / 2; i += NBLK * NTHR) {
        ull u = ((const ull*)hidden)[i];
        stA((ull*)w.h + i, u);
        stA((uint*)w.hbf + i, f2bf(ulo(u)) | (f2bf(uhi(u)) << 16));
    }
    for (int i = bid * NTHR + tid; i < Vn * Hn / 4; i += NBLK * NTHR) {
        float4 v = ((const float4*)W_proj)[i];
        ull o = (ull)(f2bf(v.x) | (f2bf(v.y) << 16))
              | ((ull)(f2bf(v.z) | (f2bf(v.w) << 16)) << 32);
        stA((ull*)w.wbf + i, o);
    }
    for (int r = bid * NTHR + tid; r < Vn; r += NBLK * NTHR) {
        const float4* wr = (const float4*)(W_proj + (size_t)r * Hn);
        float s0 = 0.f, s1 = 0.f;
        for (int e = 0; e < 128; e += 2) {
            float4 a = wr[e], b4 = wr[e + 1];
            s0 += a.x * a.x + a.z * a.z + b4.x * b4.x + b4.z * b4.z;
            s1 += a.y * a.y + a.w * a.w + b4.y * b4.y + b4.w * b4.w;
        }
        stA(&w.wn[r], sqrtf(s0 + s1) * 1.0005f);
    }
}

// ---- gh sub-phase: threads 832..1023 = 32 b x 6 k-splits, exact fp32 ----
__device__ void do_gh(int tid, int bid, const float* __restrict__ W_hh,
                      const float* __restrict__ h, SM* sm)
{
    if (tid < 832) return;
    int idx = tid - 832;                 // 0..191
    int b = idx & 31, ks = idx >> 5;     // ks in [0,6)
    int f40 = ks * 21 + (ks < 2 ? ks : 2);
    int nf4 = 21 + (ks < 2 ? 1 : 0);
    const ull* hp = (const ull*)h + b * 256 + f40 * 2;
    const float4* wr[GPB];
    #pragma unroll
    for (int r6 = 0; r6 < GPB; ++r6)
        wr[r6] = (const float4*)(W_hh + (size_t)(bid * GPB + r6) * Hn) + f40;
    float p[GPB];
    #pragma unroll
    for (int r6 = 0; r6 < GPB; ++r6) p[r6] = 0.f;
    for (int e = 0; e < nf4; ++e) {
        ull u0 = ldA(hp + 2 * e), u1 = ldA(hp + 2 * e + 1);
        float h0 = ulo(u0), h1 = uhi(u0), h2 = ulo(u1), h3 = uhi(u1);
        #pragma unroll
        for (int r6 = 0; r6 < GPB; ++r6) {
            float4 wv4 = wr[r6][e];
            p[r6] += wv4.x * h0 + wv4.y * h1 + wv4.z * h2 + wv4.w * h3;
        }
    }
    #pragma unroll
    for (int r6 = 0; r6 < GPB; ++r6)
        sm->ghsc[(r6 * 32 + b) * 6 + ks] = p[r6];
}
// fin_gh over threads [base, base+192)
__device__ void fin_gh(int tid, int base, int bid, const float* __restrict__ b_hh,
                       float* __restrict__ gh, SM* sm)
{
    if (tid >= base && tid < base + 192) {
        int idx = tid - base;
        int r6 = idx >> 5, b = idx & 31;
        float s = 0.f;
        #pragma unroll
        for (int j = 0; j < 6; ++j) s += sm->ghsc[(r6 * 32 + b) * 6 + j];
        int r = bid * GPB + r6;
        stA(&gh[(size_t)b * G3H + r], s + b_hh[r]);
    }
}

// ---- Phase B (merged, barrier-free lb): MFMA logits -> own-lb selection ->
//      fresh-lb refilter -> exact recheck -> es publish ----
// waves 0-7: one 16-row W tile each (tail masked), 2 batch sub-tiles, K=512.
// A-fragments preloaded into av[16] and PINNED with sched_barrier(0) so the
// 16 loads stay in flight under h-staging + barrier (R4's preload was sunk
// back into the loop by the scheduler; this is the fix).
// D layout (m89): col=lane&15 (batch), row=(lane>>4)*4+reg (W row).
__device__ __forceinline__ void phase_bc(int tid, int bid, int t, WS w,
                         const float* __restrict__ W_hh, const float* __restrict__ b_hh,
                         const float* __restrict__ W_proj, const float* __restrict__ b_proj,
                         SM* sm)
{
    const int lane = tid & 63, wv = tid >> 6;

    uint4 av[16];
    if (wv < 8) {
        int arow = bid * VPB + wv * 16 + (lane & 15);
        if (arow > Vn - 1) arow = Vn - 1;            // tail clamp (masked later)
        const uint4* wp = (const uint4*)w.wbf + (size_t)arow * 64 + (lane >> 4);
        #pragma unroll
        for (int ks = 0; ks < 16; ++ks) av[ks] = wp[ks * 4];
    }
    __builtin_amdgcn_sched_barrier(0);               // pin: loads issue HERE

    // stage h-hat (bf16, pre-packed by writers) into LDS, swizzled
    for (int i = tid; i < 2048; i += NTHR) {
        int bb = i >> 6, e8 = i & 63;
        const ull* hs = (const ull*)w.hbf + (size_t)bb * 128 + e8 * 2;
        ull u0 = ldA(hs), u1 = ldA(hs + 1);
        uint4 P;
        P.x = (uint)u0; P.y = (uint)(u0 >> 32);
        P.z = (uint)u1; P.w = (uint)(u1 >> 32);
        sm->h4[(bb << 6) + (e8 ^ bb)] = P;
    }
    __syncthreads();

    do_gh(tid, bid, W_hh, w.h, sm);                  // waves 13-15

    if (tid >= 800 && tid < 832) {                   // norm group
        int b = tid & 31;
        float s = 0.f;
        for (int e8 = 0; e8 < 64; ++e8) {
            uint4 H = sm->h4[(b << 6) + (e8 ^ b)];
            float f0=bflo(H.x),f1=bfhi(H.x),f2=bflo(H.y),f3=bfhi(H.y);
            float f4=bflo(H.z),f5=bfhi(H.z),f6=bflo(H.w),f7=bfhi(H.w);
            s += f0*f0+f1*f1+f2*f2+f3*f3+f4*f4+f5*f5+f6*f6+f7*f7;
        }
        sm->hn[b] = CE * sqrtf(s);
    }

    f32x4 c0 = (f32x4){0.f,0.f,0.f,0.f}, c1 = (f32x4){0.f,0.f,0.f,0.f};
    if (wv < 8) {
        const int bb0 = lane & 15, bb1 = bb0 + 16;
        const int i0 = bb0 << 6, i1 = bb1 << 6;
        const int eb = lane >> 4;
        #pragma unroll
        for (int ks = 0; ks < 16; ++ks) {
            int e8 = ks * 4 + eb;
            uint4 b0 = sm->h4[i0 + (e8 ^ bb0)];
            uint4 b1 = sm->h4[i1 + (e8 ^ bb1)];
            c0 = __builtin_amdgcn_mfma_f32_16x16x32_bf16(u2b(av[ks]), u2b(b0), c0, 0, 0, 0);
            c1 = __builtin_amdgcn_mfma_f32_16x16x32_bf16(u2b(av[ks]), u2b(b1), c1, 0, 0, 0);
        }
    }
    __syncthreads();                                 // hn + ghsc ready

    const int rl0 = wv * 16 + ((lane >> 4) << 2);
    float bp[4], wnr[4];
    if (wv < 8) {                                    // bound keys
        ull k0 = 0ull, k1 = 0ull;
        const float hn0 = sm->hn[lane & 15], hn1 = sm->hn[(lane & 15) + 16];
        #pragma unroll
        for (int j = 0; j < 4; ++j) {
            int rl = rl0 + j;
            if (rl < VPB) {
                int r = bid * VPB + rl;
                bp[j] = b_proj[r]; wnr[j] = w.wn[r];
                ull q0 = ((ull)fkey(c0[j] + bp[j] - hn0 * wnr[j])) << 32;
                ull q1 = ((ull)fkey(c1[j] + bp[j] - hn1 * wnr[j])) << 32;
                if (q0 > k0) k0 = q0;
                if (q1 > k1) k1 = q1;
            }
        }
        ull o;
        o = __shfl_xor(k0, 16); if (o > k0) k0 = o;
        o = __shfl_xor(k0, 32); if (o > k0) k0 = o;
        o = __shfl_xor(k1, 16); if (o > k1) k1 = o;
        o = __shfl_xor(k1, 32); if (o > k1) k1 = o;
        if (lane < 16) sm->red[(wv << 5) + lane] = k0;
        else if (lane < 32) sm->red[(wv << 5) + 16 + (lane & 15)] = k1;
    }
    __syncthreads();

    if (tid < Bn) {                                  // reduce + PUBLISH (no barrier)
        ull m = sm->red[tid];
        #pragma unroll
        for (int s = 1; s < 8; ++s) {
            ull v = sm->red[(s << 5) + tid];
            if (v > m) m = v;
        }
        if (m != 0ull)
            atomicMax(&w.lbs[((size_t)(t & 1) * 8 + (bid & 7)) * Bn + tid], m);
        sm->lbv[tid] = (m != 0ull) ? ifkey((uint)(m >> 32)) : -INFINITY;
    }
    if (tid == Bn) sm->cnt = 0;
    __syncthreads();

    // selection vs OWN-block lb (superset); fin_gh on idle waves 8-10 widens
    // the publish->refilter-read window
    if (wv < 8) {
        #pragma unroll
        for (int tile = 0; tile < 2; ++tile) {
            const int b = (lane & 15) + (tile << 4);
            const float hnb = sm->hn[b], lb = sm->lbv[b];
            #pragma unroll
            for (int j = 0; j < 4; ++j) {
                int rl = rl0 + j;
                if (rl < VPB) {
                    float L = (tile ? c1[j] : c0[j]) + bp[j];
                    float U = L + hnb * wnr[j];
                    if (U >= lb) {
                        int ix = atomicAdd(&sm->cnt, 1);
                        if (ix < LCAP) {
                            sm->sidx[ix] = (unsigned short)((rl << 5) | b);
                            sm->sU[ix] = U;
                        }
                    }
                }
            }
        }
    }
    fin_gh(tid, 512, bid, b_hh, w.gh, sm);           // waves 8-10
    __syncthreads();

    if (tid < Bn) {                                  // fresh global lb (refilter)
        const ull* sl = w.lbs + (size_t)(t & 1) * (8 * Bn);
        ull m = ldA(&sl[tid]);
        #pragma unroll
        for (int s = 1; s < 8; ++s) {
            ull v = ldA(&sl[s * Bn + tid]);
            if (v > m) m = v;
        }
        sm->lbv2[tid] = (m != 0ull) ? ifkey((uint)(m >> 32)) : -INFINITY;
    }
    __syncthreads();

    int nc = sm->cnt;
    if (nc <= LCAP) {
        for (int wi = wv; wi < nc; wi += 16) {       // refilter + exact recheck
            uint e = sm->sidx[wi];
            int bb = (int)(e & 31);
            if (sm->sU[wi] < sm->lbv2[bb]) continue; // stale-lb false positive
            int r = bid * VPB + (int)(e >> 5);
            const float4* wr = (const float4*)(W_proj + (size_t)r * Hn) + lane * 2;
            float4 wA = wr[0], wB = wr[1];
            const ull* hp = (const ull*)w.h + bb * 256 + lane * 4;
            ull u0 = ldA(hp), u1 = ldA(hp + 1), u2 = ldA(hp + 2), u3 = ldA(hp + 3);
            float s = wA.x*ulo(u0) + wA.y*uhi(u0) + wA.z*ulo(u1) + wA.w*uhi(u1)
                    + wB.x*ulo(u2) + wB.y*uhi(u2) + wB.z*ulo(u3) + wB.w*uhi(u3);
            #pragma unroll
            for (int d = 1; d < 64; d <<= 1) s += __shfl_xor(s, d);
            if (lane == 0) {
                s += b_proj[r];
                ull q = ((ull)fkey(s) << 32) | (uint)(~(uint)r);
                atomicMax(&w.es[((size_t)(t & 1) * 8 + (bid & 7)) * Bn + bb], q);
            }
        }
    } else {                                         // overflow: full scan (never in practice)
        for (int wi = wv; wi < VPB * Bn; wi += 16) {
            int r = bid * VPB + (wi >> 5), bb = wi & 31;
            const float4* wr = (const float4*)(W_proj + (size_t)r * Hn) + lane * 2;
            float4 wA = wr[0], wB = wr[1];
            const ull* hp = (const ull*)w.h + bb * 256 + lane * 4;
            ull u0 = ldA(hp), u1 = ldA(hp + 1), u2 = ldA(hp + 2), u3 = ldA(hp + 3);
            float s = wA.x*ulo(u0) + wA.y*uhi(u0) + wA.z*ulo(u1) + wA.w*uhi(u1)
                    + wB.x*ulo(u2) + wB.y*uhi(u2) + wB.z*ulo(u3) + wB.w*uhi(u3);
            #pragma unroll
            for (int d = 1; d < 64; d <<= 1) s += __shfl_xor(s, d);
            if (lane == 0) {
                s += b_proj[r];
                ull q = ((ull)fkey(s) << 32) | (uint)(~(uint)r);
                atomicMax(&w.es[((size_t)(t & 1) * 8 + (bid & 7)) * Bn + bb], q);
            }
        }
    }
}

// ---- Phase A: token resolve + embed/gx + gate combine + h update ----
__device__ __forceinline__ void phase_a(int tid, int bid, int t, int T,
                        const float* __restrict__ emb, const float* __restrict__ W_ih,
                        const float* __restrict__ b_ih, WS w, int* __restrict__ out, SM* sm)
{
    // hoist token-independent gh loads (cross-XCD latency overlaps resolve)
    float ghr = 0.f, ghz = 0.f, ghn = 0.f;
    const int col_a = bid + ((tid >> 5) << 8);
    if (tid < 64 && t < T) {
        int b = tid & 31;
        const float* ghrow = w.gh + (size_t)b * G3H;
        ghr = ldA(&ghrow[col_a]);
        ghz = ldA(&ghrow[Hn + col_a]);
        ghn = ldA(&ghrow[2 * Hn + col_a]);
    }
    if (tid < Bn) {
        int b = tid, tok, dnew;
        if (t == 0) { tok = SOS_TOK; dnew = 0; }
        else {
            const ull* sl = w.es + (size_t)((t - 1) & 1) * (8 * Bn);
            ull m = ldA(&sl[b]);
            #pragma unroll
            for (int s = 1; s < 8; ++s) {
                ull v = ldA(&sl[s * Bn + b]);
                if (v > m) m = v;
            }
            int idx = (int)(~(uint)m);
            int dold = ldA(&w.done[((t - 1) & 1) * Bn + b]);
            tok = dold ? EOS_TOK : idx;
            dnew = dold | (idx == EOS_TOK);
        }
        sm->tok[b] = tok;
        if (bid == 0) {
            stA(&w.done[(t & 1) * Bn + b], dnew);
            if (t > 0) out[(size_t)(t - 1) * Bn + b] = tok;
            ull* s1 = w.es  + (size_t)(t & 1) * (8 * Bn);
            ull* s2 = w.lbs + (size_t)(t & 1) * (8 * Bn);
            #pragma unroll
            for (int s = 0; s < 8; ++s) { stA(&s1[s * Bn + b], 0ull); stA(&s2[s * Bn + b], 0ull); }
        }
    }
    __syncthreads();
    if (t >= T) return;

    if (tid < 768) {
        int d = tid >> 2, q = tid & 3;
        int b = d & 31, rem = d >> 5, gate = rem >> 1, ci = rem & 1;
        int col = bid + (ci << 8);
        const float* wrow = W_ih + (size_t)(gate * Hn + col) * En + q * (En / 4);
        const float* xrow = emb + (size_t)sm->tok[b] * En + q * (En / 4);
        float ax = 0.f, ay = 0.f;
        #pragma unroll
        for (int e4 = 0; e4 < En / 16; ++e4) {
            float4 w4 = *(const float4*)(wrow + 4 * e4);
            float4 x4 = *(const float4*)(xrow + 4 * e4);
            ax = fmaf(x4.x, w4.x, ax); ay = fmaf(x4.y, w4.y, ay);
            ax = fmaf(x4.z, w4.z, ax); ay = fmaf(x4.w, w4.w, ay);
        }
        float a = ax + ay;
        a += __shfl_xor(a, 1);
        a += __shfl_xor(a, 2);
        if (q == 0) sm->gx[(ci * 3 + gate) * 32 + b] = a;
    }
    __syncthreads();

    if (tid < 64) {
        int b = tid & 31, ci = tid >> 5;
        int col = col_a;
        float gxr = sm->gx[(ci * 3 + 0) * 32 + b] + b_ih[col];
        float gxz = sm->gx[(ci * 3 + 1) * 32 + b] + b_ih[Hn + col];
        float gxn = sm->gx[(ci * 3 + 2) * 32 + b] + b_ih[2 * Hn + col];
        float r = 1.0f / (1.0f + expf(-(gxr + ghr)));
        float z = 1.0f / (1.0f + expf(-(gxz + ghz)));
        float n = tanhf(gxn + r * ghn);
        float* hp = w.h + (size_t)b * Hn + col;
        float hold = ldA(hp);
        float hnew = (1.0f - z) * n + z * hold;
        stA(hp, hnew);
        stA(&w.hbf[(size_t)b * Hn + col], (unsigned short)f2bf(hnew));
    }
}

// ================= cooperative single-kernel path =================
__global__ void __launch_bounds__(NTHR, 4)
decode_coop(const float* __restrict__ hidden, const float* __restrict__ emb,
            const float* __restrict__ W_ih, const float* __restrict__ W_hh,
            const float* __restrict__ b_ih, const float* __restrict__ b_hh,
            const float* __restrict__ W_proj, const float* __restrict__ b_proj,
            const int* __restrict__ max_len_p, int* __restrict__ out, void* ws_raw)
{
    const int tid = threadIdx.x, bid = blockIdx.x;
    __shared__ SM sm;
    WS w = get_ws(ws_raw);
    const int T = max_len_p[0];

    prologue(tid, bid, hidden, W_proj, w);
    grid_barrier(bid);
    do_gh(tid, bid, W_hh, w.h, &sm);                 // gh(h0)
    __syncthreads();
    fin_gh(tid, 0, bid, b_hh, w.gh, &sm);
    grid_barrier(bid);

    for (int t = 0; t < T; ++t) {
        phase_a(tid, bid, t, T, emb, W_ih, b_ih, w, out, &sm);
        grid_barrier(bid);
        phase_bc(tid, bid, t, w, W_hh, b_hh, W_proj, b_proj, &sm);
        grid_barrier(bid);
    }
    phase_a(tid, bid, T, T, emb, W_ih, b_ih, w, out, &sm);
}

// ================= non-cooperative fallback path =================
__global__ void __launch_bounds__(NTHR, 4)
k_pro(const float* __restrict__ hidden, const float* __restrict__ W_proj, void* ws_raw) {
    WS w = get_ws(ws_raw);
    prologue(threadIdx.x, blockIdx.x, hidden, W_proj, w);
}
__global__ void __launch_bounds__(NTHR, 4)
k_pre(const float* __restrict__ W_hh, const float* __restrict__ b_hh, void* ws_raw) {
    __shared__ SM sm;
    WS w = get_ws(ws_raw);
    do_gh(threadIdx.x, blockIdx.x, W_hh, w.h, &sm);
    __syncthreads();
    fin_gh(threadIdx.x, 0, blockIdx.x, b_hh, w.gh, &sm);
}
__global__ void __launch_bounds__(NTHR, 4)
k_a(int t, const int* __restrict__ max_len_p,
    const float* __restrict__ emb, const float* __restrict__ W_ih,
    const float* __restrict__ b_ih, int* __restrict__ out, void* ws_raw)
{
    int T = max_len_p[0];
    if (t > T) return;
    __shared__ SM sm;
    WS w = get_ws(ws_raw);
    phase_a(threadIdx.x, blockIdx.x, t, T, emb, W_ih, b_ih, w, out, &sm);
}
__global__ void __launch_bounds__(NTHR, 4)
k_bc(int t, const int* __restrict__ max_len_p,
     const float* __restrict__ W_hh, const float* __restrict__ b_hh,
     const float* __restrict__ W_proj, const float* __restrict__ b_proj, void* ws_raw)
{
    if (t >= max_len_p[0]) return;
    __shared__ SM sm;
    WS w = get_ws(ws_raw);
    phase_bc(threadIdx.x, blockIdx.x, t, w, W_hh, b_hh, W_proj, b_proj, &sm);
}

extern "C" void kernel_launch(void* const* d_in, const int* in_sizes, int n_in,
                              void* d_out, int out_size, void* d_ws, size_t ws_size,
                              hipStream_t stream) {
    const float* hidden = (const float*)d_in[0];
    const float* emb    = (const float*)d_in[1];
    const float* W_ih   = (const float*)d_in[2];
    const float* W_hh   = (const float*)d_in[3];
    const float* b_ih   = (const float*)d_in[4];
    const float* b_hh   = (const float*)d_in[5];
    const float* W_proj = (const float*)d_in[6];
    const float* b_proj = (const float*)d_in[7];
    const int* max_len  = (const int*)d_in[8];
    int* out = (int*)d_out;
    void* ws = d_ws;

    void* args[] = {&hidden, &emb, &W_ih, &W_hh, &b_ih, &b_hh,
                    &W_proj, &b_proj, &max_len, &out, &ws};
    hipError_t err = hipLaunchCooperativeKernel((const void*)decode_coop,
                                                dim3(NBLK), dim3(NTHR), args, 0, stream);
    if (err != hipSuccess) {
        (void)hipGetLastError();   // deterministic fallback chain
        hipLaunchKernelGGL(k_pro, dim3(NBLK), dim3(NTHR), 0, stream, hidden, W_proj, ws);
        hipLaunchKernelGGL(k_pre, dim3(NBLK), dim3(NTHR), 0, stream, W_hh, b_hh, ws);
        for (int t = 0; t <= 64; ++t) {
            hipLaunchKernelGGL(k_a, dim3(NBLK), dim3(NTHR), 0, stream,
                               t, max_len, emb, W_ih, b_ih, out, ws);
            if (t < 64) {
                hipLaunchKernelGGL(k_bc, dim3(NBLK), dim3(NTHR), 0, stream,
                                   t, max_len, W_hh, b_hh, W_proj, b_proj, ws);
            }
        }
    }
}

// Round 7
// 4855.040 us; speedup vs baseline: 1.0196x; 1.0196x over previous
//
#include <hip/hip_runtime.h>
#include <math.h>

#define EOS_TOK 1
#define SOS_TOK 2
#define Bn 32
#define Hn 512
#define En 256
#define Vn 32000
#define G3H 1536
#define NBLK 256
#define NTHR 1024
#define VPB 125                  // V rows per block (256*125 = 32000 exact)
#define GPB 6                    // gh rows per block (256*6 = 1536 exact)
#define CE 0.0085f               // rigorous bf16 logit error coefficient
#define LCAP 1024                // candidate list; overflow -> full-scan fallback
#define RRES 80                  // LDS-resident W rows (waves 0-4); 45 streamed

typedef unsigned long long ull;
typedef unsigned int uint;
typedef __attribute__((ext_vector_type(8))) __bf16 bf16x8;
typedef __attribute__((ext_vector_type(4))) float f32x4;

union U4B { uint4 u; bf16x8 b; };
__device__ __forceinline__ bf16x8 u2b(uint4 u) { U4B x; x.u = u; return x.b; }

// ---- workspace layout (bytes) ----
#define WBF_OFF 0ull             // bf16 W_proj [32000][512]  (32,768,000)
#define WN_OFF  32768000ull      // row norms float[32000]
#define GH_OFF  32896000ull      // gh fp32 [32][1536]
#define ES_OFF  33092608ull      // exact slots [2][8][32] ull
#define LBS_OFF 33096704ull      // lb slots    [2][8][32] ull
#define DN_OFF  33100800ull      // done [2][32] int
#define H_OFF   33101056ull      // h fp32 [32][512]

struct WS {
    unsigned short* wbf; float* wn; float* gh; ull* es; ull* lbs; int* done; float* h;
};
__device__ __forceinline__ WS get_ws(void* p) {
    WS w;
    w.wbf = (unsigned short*)((char*)p + WBF_OFF);
    w.wn  = (float*)((char*)p + WN_OFF);
    w.gh  = (float*)((char*)p + GH_OFF);
    w.es  = (ull*)((char*)p + ES_OFF);
    w.lbs = (ull*)((char*)p + LBS_OFF);
    w.done= (int*)((char*)p + DN_OFF);
    w.h   = (float*)((char*)p + H_OFF);
    return w;
}

// ---- relaxed agent-scope accessors ----
template <typename T>
__device__ __forceinline__ T ldA(const T* p) {
    return __hip_atomic_load(p, __ATOMIC_RELAXED, __HIP_MEMORY_SCOPE_AGENT);
}
template <typename T>
__device__ __forceinline__ void stA(T* p, T v) {
    __hip_atomic_store(p, v, __ATOMIC_RELAXED, __HIP_MEMORY_SCOPE_AGENT);
}

// ---- fence-free grid barrier (proven R4+) ----
struct PadCnt { ull v; ull pad[7]; };
__device__ PadCnt g_leaf[32];
__device__ ull    g_release;

__device__ __forceinline__ void grid_barrier(int bid) {
    __syncthreads();
    if (threadIdx.x == 0) {
        __builtin_amdgcn_s_waitcnt(0);
        ull my = __hip_atomic_fetch_add(&g_leaf[bid >> 3].v, 1ull,
                                        __ATOMIC_RELAXED, __HIP_MEMORY_SCOPE_AGENT) + 1;
        ull k = (my + 7) >> 3;
        if (bid == 0) {
            ull need = k << 3;
            for (;;) {
                bool again = false;
                #pragma unroll
                for (int i = 0; i < 32; ++i) again |= (ldA(&g_leaf[i].v) < need);
                if (!again) break;
                __builtin_amdgcn_s_sleep(1);
            }
            stA(&g_release, k);
        } else {
            while (ldA(&g_release) < k) __builtin_amdgcn_s_sleep(2);
        }
        __asm__ __volatile__("" ::: "memory");
    }
    __syncthreads();
}

// ---- helpers ----
__device__ __forceinline__ uint fkey(float f) {
    uint b = __float_as_uint(f);
    return (b & 0x80000000u) ? ~b : (b | 0x80000000u);
}
__device__ __forceinline__ float ifkey(uint k) {
    uint b = (k & 0x80000000u) ? (k ^ 0x80000000u) : ~k;
    return __uint_as_float(b);
}
__device__ __forceinline__ uint f2bf(float f) {      // RN fp32->bf16
    uint u = __float_as_uint(f);
    return (u + 0x7FFFu + ((u >> 16) & 1u)) >> 16;
}
__device__ __forceinline__ float bflo(uint u) { return __uint_as_float(u << 16); }
__device__ __forceinline__ float bfhi(uint u) { return __uint_as_float(u & 0xFFFF0000u); }
__device__ __forceinline__ float ulo(ull u) { return __uint_as_float((uint)u); }
__device__ __forceinline__ float uhi(ull u) { return __uint_as_float((uint)(u >> 32)); }

// ---- LDS (~126 KB: 80KB resident W + 32KB h4 + misc) ----
struct SM {
    uint4 wres[RRES * 64];       // 80 KB resident W rows, [row][chunk ^ (row&7)]
    uint4 h4[2048];              // 32 KB bf16 h-hat, [b][e8 ^ b]
    float hn[32];                // CE * ||h-hat||
    float lbv[32];               // own-block lower bound (selection)
    float lbv2[32];              // fresh global lower bound (refilter)
    float ghsc[GPB * 32 * 6];    // gh partials [r6][b][ks]
    ull   red[256];              // 8 waves x 32 batch lb keys
    int   cnt; int pad0[3];
    unsigned short sidx[LCAP];   // candidate (rl<<5)|b  (2 KB)
    float sU[LCAP];              // candidate upper bound (4 KB)
    int   tok[32];
    float gx[192];               // [ci][gate][b]
};

// ---- prologue: h init + W bf16 conversion + row norms ----
__device__ void prologue(int tid, int bid, const float* __restrict__ hidden,
                         const float* __restrict__ W_proj, WS w)
{
    for (int i = bid * NTHR + tid; i < Bn * Hn / 2; i += NBLK * NTHR)
        stA((ull*)w.h + i, ((const ull*)hidden)[i]);
    for (int i = bid * NTHR + tid; i < Vn * Hn / 4; i += NBLK * NTHR) {
        float4 v = ((const float4*)W_proj)[i];
        ull o = (ull)(f2bf(v.x) | (f2bf(v.y) << 16))
              | ((ull)(f2bf(v.z) | (f2bf(v.w) << 16)) << 32);
        stA((ull*)w.wbf + i, o);
    }
    for (int r = bid * NTHR + tid; r < Vn; r += NBLK * NTHR) {
        const float4* wr = (const float4*)(W_proj + (size_t)r * Hn);
        float s0 = 0.f, s1 = 0.f;
        for (int e = 0; e < 128; e += 2) {
            float4 a = wr[e], b4 = wr[e + 1];
            s0 += a.x * a.x + a.z * a.z + b4.x * b4.x + b4.z * b4.z;
            s1 += a.y * a.y + a.w * a.w + b4.y * b4.y + b4.w * b4.w;
        }
        stA(&w.wn[r], sqrtf(s0 + s1) * 1.0005f);
    }
}

// ---- fill resident W tile into LDS once (after wbf is ready) ----
// chunk c of row rl stored at wres[(rl<<6) | (c ^ (rl&7))]  (XOR bank swizzle)
__device__ __forceinline__ void fill_wres(int tid, int bid, WS w, SM* sm) {
    const uint4* src = (const uint4*)w.wbf + (size_t)(bid * VPB) * 64;
    for (int i = tid; i < RRES * 64; i += NTHR) {
        int rl = i >> 6, c = i & 63;
        sm->wres[(rl << 6) | (c ^ (rl & 7))] = src[(size_t)rl * 64 + c];
    }
}

// ---- gh sub-phase: threads 832..1023 = 32 b x 6 k-splits, exact fp32 ----
__device__ void do_gh(int tid, int bid, const float* __restrict__ W_hh,
                      const float* __restrict__ h, SM* sm)
{
    if (tid < 832) return;
    int idx = tid - 832;                 // 0..191
    int b = idx & 31, ks = idx >> 5;     // ks in [0,6)
    int f40 = ks * 21 + (ks < 2 ? ks : 2);
    int nf4 = 21 + (ks < 2 ? 1 : 0);
    const ull* hp = (const ull*)h + b * 256 + f40 * 2;
    const float4* wr[GPB];
    #pragma unroll
    for (int r6 = 0; r6 < GPB; ++r6)
        wr[r6] = (const float4*)(W_hh + (size_t)(bid * GPB + r6) * Hn) + f40;
    float p[GPB];
    #pragma unroll
    for (int r6 = 0; r6 < GPB; ++r6) p[r6] = 0.f;
    for (int e = 0; e < nf4; ++e) {
        ull u0 = ldA(hp + 2 * e), u1 = ldA(hp + 2 * e + 1);
        float h0 = ulo(u0), h1 = uhi(u0), h2 = ulo(u1), h3 = uhi(u1);
        #pragma unroll
        for (int r6 = 0; r6 < GPB; ++r6) {
            float4 wv4 = wr[r6][e];
            p[r6] += wv4.x * h0 + wv4.y * h1 + wv4.z * h2 + wv4.w * h3;
        }
    }
    #pragma unroll
    for (int r6 = 0; r6 < GPB; ++r6)
        sm->ghsc[(r6 * 32 + b) * 6 + ks] = p[r6];
}
// fin_gh over threads [base, base+192)
__device__ void fin_gh(int tid, int base, int bid, const float* __restrict__ b_hh,
                       float* __restrict__ gh, SM* sm)
{
    if (tid >= base && tid < base + 192) {
        int idx = tid - base;
        int r6 = idx >> 5, b = idx & 31;
        float s = 0.f;
        #pragma unroll
        for (int j = 0; j < 6; ++j) s += sm->ghsc[(r6 * 32 + b) * 6 + j];
        int r = bid * GPB + r6;
        stA(&gh[(size_t)b * G3H + r], s + b_hh[r]);
    }
}

// ---- Phase BC (merged, barrier-free lb): MFMA logits -> own-lb selection ->
//      fresh-lb refilter -> exact recheck -> es publish ----
// waves 0-4: A-frags from resident LDS tile; waves 5-7: streamed from global.
// D layout (m89): col=lane&15 (batch), row=(lane>>4)*4+reg (W row).
__device__ __forceinline__ void phase_bc(int tid, int bid, int t, WS w,
                         const float* __restrict__ W_hh, const float* __restrict__ b_hh,
                         const float* __restrict__ W_proj, const float* __restrict__ b_proj,
                         SM* sm, bool resident)
{
    // stage h-hat (bf16) into LDS, swizzled
    for (int i = tid; i < 2048; i += NTHR) {
        int bb = i >> 6, e8 = i & 63;
        const ull* hs = (const ull*)w.h + bb * 256 + e8 * 4;
        ull a = ldA(hs), b2 = ldA(hs + 1), c = ldA(hs + 2), d = ldA(hs + 3);
        uint4 P;
        P.x = f2bf(ulo(a))  | (f2bf(uhi(a))  << 16);
        P.y = f2bf(ulo(b2)) | (f2bf(uhi(b2)) << 16);
        P.z = f2bf(ulo(c))  | (f2bf(uhi(c))  << 16);
        P.w = f2bf(ulo(d))  | (f2bf(uhi(d))  << 16);
        sm->h4[(bb << 6) + (e8 ^ bb)] = P;
    }
    __syncthreads();

    do_gh(tid, bid, W_hh, w.h, sm);                  // waves 13-15

    if (tid >= 800 && tid < 832) {                   // norm group
        int b = tid & 31;
        float s = 0.f;
        for (int e8 = 0; e8 < 64; ++e8) {
            uint4 H = sm->h4[(b << 6) + (e8 ^ b)];
            float f0=bflo(H.x),f1=bfhi(H.x),f2=bflo(H.y),f3=bfhi(H.y);
            float f4=bflo(H.z),f5=bfhi(H.z),f6=bflo(H.w),f7=bfhi(H.w);
            s += f0*f0+f1*f1+f2*f2+f3*f3+f4*f4+f5*f5+f6*f6+f7*f7;
        }
        sm->hn[b] = CE * sqrtf(s);
    }

    const int lane = tid & 63, wv = tid >> 6;
    f32x4 c0 = (f32x4){0.f,0.f,0.f,0.f}, c1 = (f32x4){0.f,0.f,0.f,0.f};
    if (wv < 8) {
        const int bb0 = lane & 15, bb1 = bb0 + 16;
        const int i0 = bb0 << 6, i1 = bb1 << 6;
        const int eb = lane >> 4;
        if (resident && wv < 5) {                    // LDS-resident A-frags
            const int rbase = ((wv << 4) + bb0) << 6;
            const int sw = lane & 7;
            #pragma unroll
            for (int ks = 0; ks < 16; ++ks) {
                uint4 av = sm->wres[rbase | (((ks << 2) | eb) ^ sw)];
                int e8 = ks * 4 + eb;
                uint4 b0 = sm->h4[i0 + (e8 ^ bb0)];
                uint4 b1 = sm->h4[i1 + (e8 ^ bb1)];
                c0 = __builtin_amdgcn_mfma_f32_16x16x32_bf16(u2b(av), u2b(b0), c0, 0, 0, 0);
                c1 = __builtin_amdgcn_mfma_f32_16x16x32_bf16(u2b(av), u2b(b1), c1, 0, 0, 0);
            }
        } else {                                     // streamed A-frags
            int arow = bid * VPB + wv * 16 + bb0;
            if (arow > Vn - 1) arow = Vn - 1;        // tail clamp (masked later)
            const uint4* wp = (const uint4*)w.wbf + (size_t)arow * 64 + eb;
            #pragma unroll
            for (int ks = 0; ks < 16; ++ks) {
                uint4 av = wp[ks * 4];
                int e8 = ks * 4 + eb;
                uint4 b0 = sm->h4[i0 + (e8 ^ bb0)];
                uint4 b1 = sm->h4[i1 + (e8 ^ bb1)];
                c0 = __builtin_amdgcn_mfma_f32_16x16x32_bf16(u2b(av), u2b(b0), c0, 0, 0, 0);
                c1 = __builtin_amdgcn_mfma_f32_16x16x32_bf16(u2b(av), u2b(b1), c1, 0, 0, 0);
            }
        }
    }
    __syncthreads();                                 // hn + ghsc ready

    const int rl0 = wv * 16 + ((lane >> 4) << 2);
    float bp[4], wnr[4];
    if (wv < 8) {                                    // bound keys
        ull k0 = 0ull, k1 = 0ull;
        const float hn0 = sm->hn[lane & 15], hn1 = sm->hn[(lane & 15) + 16];
        #pragma unroll
        for (int j = 0; j < 4; ++j) {
            int rl = rl0 + j;
            if (rl < VPB) {
                int r = bid * VPB + rl;
                bp[j] = b_proj[r]; wnr[j] = w.wn[r];
                ull q0 = ((ull)fkey(c0[j] + bp[j] - hn0 * wnr[j])) << 32;
                ull q1 = ((ull)fkey(c1[j] + bp[j] - hn1 * wnr[j])) << 32;
                if (q0 > k0) k0 = q0;
                if (q1 > k1) k1 = q1;
            }
        }
        ull o;
        o = __shfl_xor(k0, 16); if (o > k0) k0 = o;
        o = __shfl_xor(k0, 32); if (o > k0) k0 = o;
        o = __shfl_xor(k1, 16); if (o > k1) k1 = o;
        o = __shfl_xor(k1, 32); if (o > k1) k1 = o;
        if (lane < 16) sm->red[(wv << 5) + lane] = k0;
        else if (lane < 32) sm->red[(wv << 5) + 16 + (lane & 15)] = k1;
    }
    __syncthreads();

    if (tid < Bn) {                                  // reduce + PUBLISH (no barrier)
        ull m = sm->red[tid];
        #pragma unroll
        for (int s = 1; s < 8; ++s) {
            ull v = sm->red[(s << 5) + tid];
            if (v > m) m = v;
        }
        if (m != 0ull)
            atomicMax(&w.lbs[((size_t)(t & 1) * 8 + (bid & 7)) * Bn + tid], m);
        sm->lbv[tid] = (m != 0ull) ? ifkey((uint)(m >> 32)) : -INFINITY;
    }
    if (tid == Bn) sm->cnt = 0;
    __syncthreads();

    // selection vs OWN-block lb (superset); fin_gh on idle waves 8-10 widens
    // the publish->refilter-read window
    if (wv < 8) {
        #pragma unroll
        for (int tile = 0; tile < 2; ++tile) {
            const int b = (lane & 15) + (tile << 4);
            const float hnb = sm->hn[b], lb = sm->lbv[b];
            #pragma unroll
            for (int j = 0; j < 4; ++j) {
                int rl = rl0 + j;
                if (rl < VPB) {
                    float L = (tile ? c1[j] : c0[j]) + bp[j];
                    float U = L + hnb * wnr[j];
                    if (U >= lb) {
                        int ix = atomicAdd(&sm->cnt, 1);
                        if (ix < LCAP) {
                            sm->sidx[ix] = (unsigned short)((rl << 5) | b);
                            sm->sU[ix] = U;
                        }
                    }
                }
            }
        }
    }
    fin_gh(tid, 512, bid, b_hh, w.gh, sm);           // waves 8-10
    __syncthreads();

    if (tid < Bn) {                                  // fresh global lb (refilter)
        const ull* sl = w.lbs + (size_t)(t & 1) * (8 * Bn);
        ull m = ldA(&sl[tid]);
        #pragma unroll
        for (int s = 1; s < 8; ++s) {
            ull v = ldA(&sl[s * Bn + tid]);
            if (v > m) m = v;
        }
        sm->lbv2[tid] = (m != 0ull) ? ifkey((uint)(m >> 32)) : -INFINITY;
    }
    __syncthreads();

    int nc = sm->cnt;
    if (nc <= LCAP) {
        for (int wi = wv; wi < nc; wi += 16) {       // refilter + exact recheck
            uint e = sm->sidx[wi];
            int bb = (int)(e & 31);
            if (sm->sU[wi] < sm->lbv2[bb]) continue; // stale-lb false positive
            int r = bid * VPB + (int)(e >> 5);
            const float4* wr = (const float4*)(W_proj + (size_t)r * Hn) + lane * 2;
            float4 wA = wr[0], wB = wr[1];
            const ull* hp = (const ull*)w.h + bb * 256 + lane * 4;
            ull u0 = ldA(hp), u1 = ldA(hp + 1), u2 = ldA(hp + 2), u3 = ldA(hp + 3);
            float s = wA.x*ulo(u0) + wA.y*uhi(u0) + wA.z*ulo(u1) + wA.w*uhi(u1)
                    + wB.x*ulo(u2) + wB.y*uhi(u2) + wB.z*ulo(u3) + wB.w*uhi(u3);
            #pragma unroll
            for (int d = 1; d < 64; d <<= 1) s += __shfl_xor(s, d);
            if (lane == 0) {
                s += b_proj[r];
                ull q = ((ull)fkey(s) << 32) | (uint)(~(uint)r);
                atomicMax(&w.es[((size_t)(t & 1) * 8 + (bid & 7)) * Bn + bb], q);
            }
        }
    } else {                                         // overflow: full scan (never in practice)
        for (int wi = wv; wi < VPB * Bn; wi += 16) {
            int r = bid * VPB + (wi >> 5), bb = wi & 31;
            const float4* wr = (const float4*)(W_proj + (size_t)r * Hn) + lane * 2;
            float4 wA = wr[0], wB = wr[1];
            const ull* hp = (const ull*)w.h + bb * 256 + lane * 4;
            ull u0 = ldA(hp), u1 = ldA(hp + 1), u2 = ldA(hp + 2), u3 = ldA(hp + 3);
            float s = wA.x*ulo(u0) + wA.y*uhi(u0) + wA.z*ulo(u1) + wA.w*uhi(u1)
                    + wB.x*ulo(u2) + wB.y*uhi(u2) + wB.z*ulo(u3) + wB.w*uhi(u3);
            #pragma unroll
            for (int d = 1; d < 64; d <<= 1) s += __shfl_xor(s, d);
            if (lane == 0) {
                s += b_proj[r];
                ull q = ((ull)fkey(s) << 32) | (uint)(~(uint)r);
                atomicMax(&w.es[((size_t)(t & 1) * 8 + (bid & 7)) * Bn + bb], q);
            }
        }
    }
}

// ---- Phase A: token resolve + embed/gx + gate combine + h update ----
__device__ __forceinline__ void phase_a(int tid, int bid, int t, int T,
                        const float* __restrict__ emb, const float* __restrict__ W_ih,
                        const float* __restrict__ b_ih, WS w, int* __restrict__ out, SM* sm)
{
    // hoist token-independent gh loads (cross-XCD latency overlaps resolve)
    float ghr = 0.f, ghz = 0.f, ghn = 0.f;
    const int col_a = bid + ((tid >> 5) << 8);
    if (tid < 64 && t < T) {
        int b = tid & 31;
        const float* ghrow = w.gh + (size_t)b * G3H;
        ghr = ldA(&ghrow[col_a]);
        ghz = ldA(&ghrow[Hn + col_a]);
        ghn = ldA(&ghrow[2 * Hn + col_a]);
    }
    if (tid < Bn) {
        int b = tid, tok, dnew;
        if (t == 0) { tok = SOS_TOK; dnew = 0; }
        else {
            const ull* sl = w.es + (size_t)((t - 1) & 1) * (8 * Bn);
            ull m = ldA(&sl[b]);
            #pragma unroll
            for (int s = 1; s < 8; ++s) {
                ull v = ldA(&sl[s * Bn + b]);
                if (v > m) m = v;
            }
            int idx = (int)(~(uint)m);
            int dold = ldA(&w.done[((t - 1) & 1) * Bn + b]);
            tok = dold ? EOS_TOK : idx;
            dnew = dold | (idx == EOS_TOK);
        }
        sm->tok[b] = tok;
        if (bid == 0) {
            stA(&w.done[(t & 1) * Bn + b], dnew);
            if (t > 0) out[(size_t)(t - 1) * Bn + b] = tok;
            ull* s1 = w.es  + (size_t)(t & 1) * (8 * Bn);
            ull* s2 = w.lbs + (size_t)(t & 1) * (8 * Bn);
            #pragma unroll
            for (int s = 0; s < 8; ++s) { stA(&s1[s * Bn + b], 0ull); stA(&s2[s * Bn + b], 0ull); }
        }
    }
    __syncthreads();
    if (t >= T) return;

    if (tid < 768) {
        int d = tid >> 2, q = tid & 3;
        int b = d & 31, rem = d >> 5, gate = rem >> 1, ci = rem & 1;
        int col = bid + (ci << 8);
        const float* wrow = W_ih + (size_t)(gate * Hn + col) * En + q * (En / 4);
        const float* xrow = emb + (size_t)sm->tok[b] * En + q * (En / 4);
        float ax = 0.f, ay = 0.f;
        #pragma unroll
        for (int e4 = 0; e4 < En / 16; ++e4) {
            float4 w4 = *(const float4*)(wrow + 4 * e4);
            float4 x4 = *(const float4*)(xrow + 4 * e4);
            ax = fmaf(x4.x, w4.x, ax); ay = fmaf(x4.y, w4.y, ay);
            ax = fmaf(x4.z, w4.z, ax); ay = fmaf(x4.w, w4.w, ay);
        }
        float a = ax + ay;
        a += __shfl_xor(a, 1);
        a += __shfl_xor(a, 2);
        if (q == 0) sm->gx[(ci * 3 + gate) * 32 + b] = a;
    }
    __syncthreads();

    if (tid < 64) {
        int b = tid & 31, ci = tid >> 5;
        int col = col_a;
        float gxr = sm->gx[(ci * 3 + 0) * 32 + b] + b_ih[col];
        float gxz = sm->gx[(ci * 3 + 1) * 32 + b] + b_ih[Hn + col];
        float gxn = sm->gx[(ci * 3 + 2) * 32 + b] + b_ih[2 * Hn + col];
        float r = 1.0f / (1.0f + expf(-(gxr + ghr)));
        float z = 1.0f / (1.0f + expf(-(gxz + ghz)));
        float n = tanhf(gxn + r * ghn);
        float* hp = w.h + (size_t)b * Hn + col;
        float hold = ldA(hp);
        stA(hp, (1.0f - z) * n + z * hold);
    }
}

// ================= cooperative single-kernel path =================
__global__ void __launch_bounds__(NTHR, 4)
decode_coop(const float* __restrict__ hidden, const float* __restrict__ emb,
            const float* __restrict__ W_ih, const float* __restrict__ W_hh,
            const float* __restrict__ b_ih, const float* __restrict__ b_hh,
            const float* __restrict__ W_proj, const float* __restrict__ b_proj,
            const int* __restrict__ max_len_p, int* __restrict__ out, void* ws_raw)
{
    const int tid = threadIdx.x, bid = blockIdx.x;
    __shared__ SM sm;
    WS w = get_ws(ws_raw);
    const int T = max_len_p[0];

    prologue(tid, bid, hidden, W_proj, w);
    grid_barrier(bid);
    fill_wres(tid, bid, w, &sm);                     // resident W tile, once
    do_gh(tid, bid, W_hh, w.h, &sm);                 // gh(h0)
    __syncthreads();
    fin_gh(tid, 0, bid, b_hh, w.gh, &sm);
    grid_barrier(bid);

    for (int t = 0; t < T; ++t) {
        phase_a(tid, bid, t, T, emb, W_ih, b_ih, w, out, &sm);
        grid_barrier(bid);
        phase_bc(tid, bid, t, w, W_hh, b_hh, W_proj, b_proj, &sm, true);
        grid_barrier(bid);
    }
    phase_a(tid, bid, T, T, emb, W_ih, b_ih, w, out, &sm);
}

// ================= non-cooperative fallback path =================
__global__ void __launch_bounds__(NTHR, 4)
k_pro(const float* __restrict__ hidden, const float* __restrict__ W_proj, void* ws_raw) {
    WS w = get_ws(ws_raw);
    prologue(threadIdx.x, blockIdx.x, hidden, W_proj, w);
}
__global__ void __launch_bounds__(NTHR, 4)
k_pre(const float* __restrict__ W_hh, const float* __restrict__ b_hh, void* ws_raw) {
    __shared__ SM sm;
    WS w = get_ws(ws_raw);
    do_gh(threadIdx.x, blockIdx.x, W_hh, w.h, &sm);
    __syncthreads();
    fin_gh(threadIdx.x, 0, blockIdx.x, b_hh, w.gh, &sm);
}
__global__ void __launch_bounds__(NTHR, 4)
k_a(int t, const int* __restrict__ max_len_p,
    const float* __restrict__ emb, const float* __restrict__ W_ih,
    const float* __restrict__ b_ih, int* __restrict__ out, void* ws_raw)
{
    int T = max_len_p[0];
    if (t > T) return;
    __shared__ SM sm;
    WS w = get_ws(ws_raw);
    phase_a(threadIdx.x, blockIdx.x, t, T, emb, W_ih, b_ih, w, out, &sm);
}
__global__ void __launch_bounds__(NTHR, 4)
k_bc(int t, const int* __restrict__ max_len_p,
     const float* __restrict__ W_hh, const float* __restrict__ b_hh,
     const float* __restrict__ W_proj, const float* __restrict__ b_proj, void* ws_raw)
{
    if (t >= max_len_p[0]) return;
    __shared__ SM sm;
    WS w = get_ws(ws_raw);
    phase_bc(threadIdx.x, blockIdx.x, t, w, W_hh, b_hh, W_proj, b_proj, &sm, false);
}

extern "C" void kernel_launch(void* const* d_in, const int* in_sizes, int n_in,
                              void* d_out, int out_size, void* d_ws, size_t ws_size,
                              hipStream_t stream) {
    const float* hidden = (const float*)d_in[0];
    const float* emb    = (const float*)d_in[1];
    const float* W_ih   = (const float*)d_in[2];
    const float* W_hh   = (const float*)d_in[3];
    const float* b_ih   = (const float*)d_in[4];
    const float* b_hh   = (const float*)d_in[5];
    const float* W_proj = (const float*)d_in[6];
    const float* b_proj = (const float*)d_in[7];
    const int* max_len  = (const int*)d_in[8];
    int* out = (int*)d_out;
    void* ws = d_ws;

    void* args[] = {&hidden, &emb, &W_ih, &W_hh, &b_ih, &b_hh,
                    &W_proj, &b_proj, &max_len, &out, &ws};
    hipError_t err = hipLaunchCooperativeKernel((const void*)decode_coop,
                                                dim3(NBLK), dim3(NTHR), args, 0, stream);
    if (err != hipSuccess) {
        (void)hipGetLastError();   // deterministic fallback chain
        hipLaunchKernelGGL(k_pro, dim3(NBLK), dim3(NTHR), 0, stream, hidden, W_proj, ws);
        hipLaunchKernelGGL(k_pre, dim3(NBLK), dim3(NTHR), 0, stream, W_hh, b_hh, ws);
        for (int t = 0; t <= 64; ++t) {
            hipLaunchKernelGGL(k_a, dim3(NBLK), dim3(NTHR), 0, stream,
                               t, max_len, emb, W_ih, b_ih, out, ws);
            if (t < 64) {
                hipLaunchKernelGGL(k_bc, dim3(NBLK), dim3(NTHR), 0, stream,
                                   t, max_len, W_hh, b_hh, W_proj, b_proj, ws);
            }
        }
    }
}

// Round 8
// 3945.018 us; speedup vs baseline: 1.2548x; 1.2307x over previous
//
#include <hip/hip_runtime.h>
#include <math.h>

#define EOS_TOK 1
#define SOS_TOK 2
#define Bn 32
#define Hn 512
#define En 256
#define Vn 32000
#define G3H 1536
#define NBLK 256
#define NTHR 1024
#define VPB 125                  // V rows per block (256*125 = 32000 exact)
#define GPB 6                    // gh rows per block (256*6 = 1536 exact)
#define CE 0.0085f               // rigorous bf16 logit error coefficient
#define LCAP 2048                // candidate list; overflow -> full-scan fallback

typedef unsigned long long ull;
typedef unsigned int uint;
typedef __attribute__((ext_vector_type(8))) __bf16 bf16x8;
typedef __attribute__((ext_vector_type(4))) float f32x4;

union U4B { uint4 u; bf16x8 b; };
__device__ __forceinline__ bf16x8 u2b(uint4 u) { U4B x; x.u = u; return x.b; }

// ---- workspace layout (bytes) ----
#define WBF_OFF 0ull             // bf16 W_proj [32000][512]  (32,768,000)
#define WN_OFF  32768000ull      // row norms float[32000]
#define GH_OFF  32896000ull      // gh fp32 [32][1536]
#define ES_OFF  33092608ull      // exact slots [2][8][32] ull
#define LBS_OFF 33096704ull      // lb slots    [2][8][32] ull
#define DN_OFF  33100800ull      // done [2][32] int
#define H_OFF   33101056ull      // h fp32 [32][512]

struct WS {
    unsigned short* wbf; float* wn; float* gh; ull* es; ull* lbs; int* done; float* h;
};
__device__ __forceinline__ WS get_ws(void* p) {
    WS w;
    w.wbf = (unsigned short*)((char*)p + WBF_OFF);
    w.wn  = (float*)((char*)p + WN_OFF);
    w.gh  = (float*)((char*)p + GH_OFF);
    w.es  = (ull*)((char*)p + ES_OFF);
    w.lbs = (ull*)((char*)p + LBS_OFF);
    w.done= (int*)((char*)p + DN_OFF);
    w.h   = (float*)((char*)p + H_OFF);
    return w;
}

// ---- relaxed agent-scope accessors ----
template <typename T>
__device__ __forceinline__ T ldA(const T* p) {
    return __hip_atomic_load(p, __ATOMIC_RELAXED, __HIP_MEMORY_SCOPE_AGENT);
}
template <typename T>
__device__ __forceinline__ void stA(T* p, T v) {
    __hip_atomic_store(p, v, __ATOMIC_RELAXED, __HIP_MEMORY_SCOPE_AGENT);
}

// ---- fence-free grid barrier (proven R4+) ----
struct PadCnt { ull v; ull pad[7]; };
__device__ PadCnt g_leaf[32];
__device__ ull    g_release;

__device__ __forceinline__ void grid_barrier(int bid) {
    __syncthreads();
    if (threadIdx.x == 0) {
        __builtin_amdgcn_s_waitcnt(0);
        ull my = __hip_atomic_fetch_add(&g_leaf[bid >> 3].v, 1ull,
                                        __ATOMIC_RELAXED, __HIP_MEMORY_SCOPE_AGENT) + 1;
        ull k = (my + 7) >> 3;
        if (bid == 0) {
            ull need = k << 3;
            for (;;) {
                bool again = false;
                #pragma unroll
                for (int i = 0; i < 32; ++i) again |= (ldA(&g_leaf[i].v) < need);
                if (!again) break;
                __builtin_amdgcn_s_sleep(1);
            }
            stA(&g_release, k);
        } else {
            while (ldA(&g_release) < k) __builtin_amdgcn_s_sleep(2);
        }
        __asm__ __volatile__("" ::: "memory");
    }
    __syncthreads();
}

// ---- helpers ----
__device__ __forceinline__ uint fkey(float f) {
    uint b = __float_as_uint(f);
    return (b & 0x80000000u) ? ~b : (b | 0x80000000u);
}
__device__ __forceinline__ float ifkey(uint k) {
    uint b = (k & 0x80000000u) ? (k ^ 0x80000000u) : ~k;
    return __uint_as_float(b);
}
__device__ __forceinline__ uint f2bf(float f) {      // RN fp32->bf16
    uint u = __float_as_uint(f);
    return (u + 0x7FFFu + ((u >> 16) & 1u)) >> 16;
}
__device__ __forceinline__ float bflo(uint u) { return __uint_as_float(u << 16); }
__device__ __forceinline__ float bfhi(uint u) { return __uint_as_float(u & 0xFFFF0000u); }
__device__ __forceinline__ float ulo(ull u) { return __uint_as_float((uint)u); }
__device__ __forceinline__ float uhi(ull u) { return __uint_as_float((uint)(u >> 32)); }

// ---- LDS (~118 KB) ----
struct SM {
    ull   hf[32 * 257];          // 65.8 KB fp32 h copy, stride 257 (2-way banks)
    uint4 h4[2048];              // 32 KB bf16 h-hat, [b][e8 ^ b]
    uint  lbk[32];               // own-block lb keys (LDS atomicMax)
    float hn[32];                // CE * ||h-hat||
    float lbv2[32];              // fresh global lower bound (refilter)
    float ghsc[GPB * 32 * 6];    // gh partials [r6][b][ks]
    int   cnt; int pad0[3];
    unsigned short sidx[LCAP];   // candidate (rl<<5)|b  (4 KB)
    float sU[LCAP];              // candidate upper bound (8 KB)
    int   tok[32];
    float gx[192];               // [ci][gate][b]
    float bpc[VPB + 3];          // b_proj cache for this block's rows
    float wnc[VPB + 3];          // wn cache
};

// ---- prologue: h init + W bf16 conversion + row norms ----
__device__ void prologue(int tid, int bid, const float* __restrict__ hidden,
                         const float* __restrict__ W_proj, WS w)
{
    for (int i = bid * NTHR + tid; i < Bn * Hn / 2; i += NBLK * NTHR)
        stA((ull*)w.h + i, ((const ull*)hidden)[i]);
    for (int i = bid * NTHR + tid; i < Vn * Hn / 4; i += NBLK * NTHR) {
        float4 v = ((const float4*)W_proj)[i];
        ull o = (ull)(f2bf(v.x) | (f2bf(v.y) << 16))
              | ((ull)(f2bf(v.z) | (f2bf(v.w) << 16)) << 32);
        stA((ull*)w.wbf + i, o);
    }
    for (int r = bid * NTHR + tid; r < Vn; r += NBLK * NTHR) {
        const float4* wr = (const float4*)(W_proj + (size_t)r * Hn);
        float s0 = 0.f, s1 = 0.f;
        for (int e = 0; e < 128; e += 2) {
            float4 a = wr[e], b4 = wr[e + 1];
            s0 += a.x * a.x + a.z * a.z + b4.x * b4.x + b4.z * b4.z;
            s1 += a.y * a.y + a.w * a.w + b4.y * b4.y + b4.w * b4.w;
        }
        stA(&w.wn[r], sqrtf(s0 + s1) * 1.0005f);
    }
}

// ---- stage h into LDS: fp32 copy (hf) + swizzled bf16 (h4), one global read ----
__device__ __forceinline__ void stage_h(int tid, WS w, SM* sm) {
    for (int i = tid; i < 2048; i += NTHR) {
        int bb = i >> 6, e8 = i & 63;
        const ull* hs = (const ull*)w.h + bb * 256 + e8 * 4;
        ull a = ldA(hs), b2 = ldA(hs + 1), c = ldA(hs + 2), d = ldA(hs + 3);
        ull* hd = sm->hf + bb * 257 + e8 * 4;
        hd[0] = a; hd[1] = b2; hd[2] = c; hd[3] = d;
        uint4 P;
        P.x = f2bf(ulo(a))  | (f2bf(uhi(a))  << 16);
        P.y = f2bf(ulo(b2)) | (f2bf(uhi(b2)) << 16);
        P.z = f2bf(ulo(c))  | (f2bf(uhi(c))  << 16);
        P.w = f2bf(ulo(d))  | (f2bf(uhi(d))  << 16);
        sm->h4[(bb << 6) + (e8 ^ bb)] = P;
    }
}

// ---- gh sub-phase: threads 832..1023 = 32 b x 6 k-splits, exact fp32 ----
// h read from LDS hf (removes 42-deep cross-XCD global chain)
__device__ void do_gh(int tid, int bid, const float* __restrict__ W_hh, SM* sm)
{
    if (tid < 832) return;
    int idx = tid - 832;                 // 0..191
    int b = idx & 31, ks = idx >> 5;     // ks in [0,6)
    int f40 = ks * 21 + (ks < 2 ? ks : 2);
    int nf4 = 21 + (ks < 2 ? 1 : 0);
    const ull* hp = sm->hf + b * 257 + f40 * 2;
    const float4* wr[GPB];
    #pragma unroll
    for (int r6 = 0; r6 < GPB; ++r6)
        wr[r6] = (const float4*)(W_hh + (size_t)(bid * GPB + r6) * Hn) + f40;
    float p[GPB];
    #pragma unroll
    for (int r6 = 0; r6 < GPB; ++r6) p[r6] = 0.f;
    for (int e = 0; e < nf4; ++e) {
        ull u0 = hp[2 * e], u1 = hp[2 * e + 1];
        float h0 = ulo(u0), h1 = uhi(u0), h2 = ulo(u1), h3 = uhi(u1);
        #pragma unroll
        for (int r6 = 0; r6 < GPB; ++r6) {
            float4 wv4 = wr[r6][e];
            p[r6] += wv4.x * h0 + wv4.y * h1 + wv4.z * h2 + wv4.w * h3;
        }
    }
    #pragma unroll
    for (int r6 = 0; r6 < GPB; ++r6)
        sm->ghsc[(r6 * 32 + b) * 6 + ks] = p[r6];
}
// fin_gh over threads [base, base+192)
__device__ void fin_gh(int tid, int base, int bid, const float* __restrict__ b_hh,
                       float* __restrict__ gh, SM* sm)
{
    if (tid >= base && tid < base + 192) {
        int idx = tid - base;
        int r6 = idx >> 5, b = idx & 31;
        float s = 0.f;
        #pragma unroll
        for (int j = 0; j < 6; ++j) s += sm->ghsc[(r6 * 32 + b) * 6 + j];
        int r = bid * GPB + r6;
        stA(&gh[(size_t)b * G3H + r], s + b_hh[r]);
    }
}

// ---- Phase BC: 4-sync schedule ----
// region1: stage_h              | sync1
// region2: MFMA(wv<8) + do_gh(13-15) + norm(800-831) + inits(512-672) | sync2
// region3: bound keys -> LDS atomicMax lbk                            | sync3
// region4: publish lbs + selection + fin_gh(8-10) + refilter read     | sync4
// region5: exact recheck (hf, bpc) -> es publish
// D layout (m89): col=lane&15 (batch), row=(lane>>4)*4+reg (W row).
__device__ __forceinline__ void phase_bc(int tid, int bid, int t, WS w,
                         const float* __restrict__ W_hh, const float* __restrict__ b_hh,
                         const float* __restrict__ W_proj, const float* __restrict__ b_proj,
                         SM* sm)
{
    const int lane = tid & 63, wv = tid >> 6;

    stage_h(tid, w, sm);
    __syncthreads();                                 // sync1: hf + h4 ready

    do_gh(tid, bid, W_hh, sm);                       // waves 13-15 (LDS h)

    if (tid >= 800 && tid < 832) {                   // norm group
        int b = tid & 31;
        float s = 0.f;
        for (int e8 = 0; e8 < 64; ++e8) {
            uint4 H = sm->h4[(b << 6) + (e8 ^ b)];
            float f0=bflo(H.x),f1=bfhi(H.x),f2=bflo(H.y),f3=bfhi(H.y);
            float f4=bflo(H.z),f5=bfhi(H.z),f6=bflo(H.w),f7=bfhi(H.w);
            s += f0*f0+f1*f1+f2*f2+f3*f3+f4*f4+f5*f5+f6*f6+f7*f7;
        }
        sm->hn[b] = CE * sqrtf(s);
    }
    if (tid >= 512 && tid < 544) sm->lbk[tid - 512] = 0u;   // idle waves: inits
    if (tid >= 544 && tid < 544 + VPB) {
        int rl = tid - 544;
        sm->bpc[rl] = b_proj[bid * VPB + rl];
        sm->wnc[rl] = w.wn[bid * VPB + rl];
    }
    if (tid == 672) sm->cnt = 0;

    f32x4 c0 = (f32x4){0.f,0.f,0.f,0.f}, c1 = (f32x4){0.f,0.f,0.f,0.f};
    if (wv < 8) {
        int arow = bid * VPB + wv * 16 + (lane & 15);
        if (arow > Vn - 1) arow = Vn - 1;            // tail clamp (masked later)
        const uint4* wp = (const uint4*)w.wbf + (size_t)arow * 64 + (lane >> 4);
        const int bb0 = lane & 15, bb1 = bb0 + 16;
        const int i0 = bb0 << 6, i1 = bb1 << 6;
        const int eb = lane >> 4;
        #pragma unroll
        for (int ks = 0; ks < 16; ++ks) {
            uint4 av = wp[ks * 4];
            int e8 = ks * 4 + eb;
            uint4 b0 = sm->h4[i0 + (e8 ^ bb0)];
            uint4 b1 = sm->h4[i1 + (e8 ^ bb1)];
            c0 = __builtin_amdgcn_mfma_f32_16x16x32_bf16(u2b(av), u2b(b0), c0, 0, 0, 0);
            c1 = __builtin_amdgcn_mfma_f32_16x16x32_bf16(u2b(av), u2b(b1), c1, 0, 0, 0);
        }
    }
    __syncthreads();                                 // sync2: hn/ghsc/inits ready

    const int rl0 = wv * 16 + ((lane >> 4) << 2);
    if (wv < 8) {                                    // bound keys -> LDS atomicMax
        ull k0 = 0ull, k1 = 0ull;
        const float hn0 = sm->hn[lane & 15], hn1 = sm->hn[(lane & 15) + 16];
        #pragma unroll
        for (int j = 0; j < 4; ++j) {
            int rl = rl0 + j;
            if (rl < VPB) {
                float bp = sm->bpc[rl], wn = sm->wnc[rl];
                ull q0 = ((ull)fkey(c0[j] + bp - hn0 * wn)) << 32;
                ull q1 = ((ull)fkey(c1[j] + bp - hn1 * wn)) << 32;
                if (q0 > k0) k0 = q0;
                if (q1 > k1) k1 = q1;
            }
        }
        ull o;
        o = __shfl_xor(k0, 16); if (o > k0) k0 = o;
        o = __shfl_xor(k0, 32); if (o > k0) k0 = o;
        o = __shfl_xor(k1, 16); if (o > k1) k1 = o;
        o = __shfl_xor(k1, 32); if (o > k1) k1 = o;
        if (lane < 16) atomicMax(&sm->lbk[lane], (uint)(k0 >> 32));
        else if (lane < 32) atomicMax(&sm->lbk[16 + (lane & 15)], (uint)(k1 >> 32));
    }
    __syncthreads();                                 // sync3: lbk ready

    if (tid < Bn) {                                  // publish own lb (no barrier)
        uint k = sm->lbk[tid];
        if (k) atomicMax(&w.lbs[((size_t)(t & 1) * 8 + (bid & 7)) * Bn + tid],
                         ((ull)k) << 32);
    }
    if (wv < 8) {                                    // selection vs own-block lb
        #pragma unroll
        for (int tile = 0; tile < 2; ++tile) {
            const int b = (lane & 15) + (tile << 4);
            const float hnb = sm->hn[b], lb = ifkey(sm->lbk[b]);
            #pragma unroll
            for (int j = 0; j < 4; ++j) {
                int rl = rl0 + j;
                if (rl < VPB) {
                    float L = (tile ? c1[j] : c0[j]) + sm->bpc[rl];
                    float U = L + hnb * sm->wnc[rl];
                    if (U >= lb) {
                        int ix = atomicAdd(&sm->cnt, 1);
                        if (ix < LCAP) {
                            sm->sidx[ix] = (unsigned short)((rl << 5) | b);
                            sm->sU[ix] = U;
                        }
                    }
                }
            }
        }
    }
    fin_gh(tid, 512, bid, b_hh, w.gh, sm);           // waves 8-10
    __builtin_amdgcn_sched_barrier(0);               // keep refilter read late
    if (tid < Bn) {                                  // fresh global lb (refilter)
        const ull* sl = w.lbs + (size_t)(t & 1) * (8 * Bn);
        ull m = ldA(&sl[tid]);
        #pragma unroll
        for (int s = 1; s < 8; ++s) {
            ull v = ldA(&sl[s * Bn + tid]);
            if (v > m) m = v;
        }
        sm->lbv2[tid] = (m != 0ull) ? ifkey((uint)(m >> 32)) : -INFINITY;
    }
    __syncthreads();                                 // sync4: cnt/sidx/sU/lbv2

    int nc = sm->cnt;
    if (nc <= LCAP) {
        for (int wi = wv; wi < nc; wi += 16) {       // refilter + exact recheck
            uint e = sm->sidx[wi];
            int bb = (int)(e & 31);
            if (sm->sU[wi] < sm->lbv2[bb]) continue; // stale-lb false positive
            int rl = (int)(e >> 5);
            int r = bid * VPB + rl;
            const float4* wr = (const float4*)(W_proj + (size_t)r * Hn) + lane * 2;
            float4 wA = wr[0], wB = wr[1];
            const ull* hp = sm->hf + bb * 257 + lane * 4;
            ull u0 = hp[0], u1 = hp[1], u2 = hp[2], u3 = hp[3];
            float s = wA.x*ulo(u0) + wA.y*uhi(u0) + wA.z*ulo(u1) + wA.w*uhi(u1)
                    + wB.x*ulo(u2) + wB.y*uhi(u2) + wB.z*ulo(u3) + wB.w*uhi(u3);
            #pragma unroll
            for (int d = 1; d < 64; d <<= 1) s += __shfl_xor(s, d);
            if (lane == 0) {
                s += sm->bpc[rl];
                ull q = ((ull)fkey(s) << 32) | (uint)(~(uint)r);
                atomicMax(&w.es[((size_t)(t & 1) * 8 + (bid & 7)) * Bn + bb], q);
            }
        }
    } else {                                         // overflow: full scan (never in practice)
        for (int wi = wv; wi < VPB * Bn; wi += 16) {
            int rl = wi >> 5, bb = wi & 31;
            int r = bid * VPB + rl;
            const float4* wr = (const float4*)(W_proj + (size_t)r * Hn) + lane * 2;
            float4 wA = wr[0], wB = wr[1];
            const ull* hp = sm->hf + bb * 257 + lane * 4;
            ull u0 = hp[0], u1 = hp[1], u2 = hp[2], u3 = hp[3];
            float s = wA.x*ulo(u0) + wA.y*uhi(u0) + wA.z*ulo(u1) + wA.w*uhi(u1)
                    + wB.x*ulo(u2) + wB.y*uhi(u2) + wB.z*ulo(u3) + wB.w*uhi(u3);
            #pragma unroll
            for (int d = 1; d < 64; d <<= 1) s += __shfl_xor(s, d);
            if (lane == 0) {
                s += sm->bpc[rl];
                ull q = ((ull)fkey(s) << 32) | (uint)(~(uint)r);
                atomicMax(&w.es[((size_t)(t & 1) * 8 + (bid & 7)) * Bn + bb], q);
            }
        }
    }
}

// ---- Phase A: token resolve + embed/gx + gate combine + h update ----
__device__ __forceinline__ void phase_a(int tid, int bid, int t, int T,
                        const float* __restrict__ emb, const float* __restrict__ W_ih,
                        const float* __restrict__ b_ih, WS w, int* __restrict__ out, SM* sm)
{
    // hoist token-independent gh loads (cross-XCD latency overlaps resolve)
    float ghr = 0.f, ghz = 0.f, ghn = 0.f;
    const int col_a = bid + ((tid >> 5) << 8);
    if (tid < 64 && t < T) {
        int b = tid & 31;
        const float* ghrow = w.gh + (size_t)b * G3H;
        ghr = ldA(&ghrow[col_a]);
        ghz = ldA(&ghrow[Hn + col_a]);
        ghn = ldA(&ghrow[2 * Hn + col_a]);
    }
    if (tid < Bn) {
        int b = tid, tok, dnew;
        if (t == 0) { tok = SOS_TOK; dnew = 0; }
        else {
            const ull* sl = w.es + (size_t)((t - 1) & 1) * (8 * Bn);
            ull m = ldA(&sl[b]);
            #pragma unroll
            for (int s = 1; s < 8; ++s) {
                ull v = ldA(&sl[s * Bn + b]);
                if (v > m) m = v;
            }
            int idx = (int)(~(uint)m);
            int dold = ldA(&w.done[((t - 1) & 1) * Bn + b]);
            tok = dold ? EOS_TOK : idx;
            dnew = dold | (idx == EOS_TOK);
        }
        sm->tok[b] = tok;
        if (bid == 0) {
            stA(&w.done[(t & 1) * Bn + b], dnew);
            if (t > 0) out[(size_t)(t - 1) * Bn + b] = tok;
            ull* s1 = w.es  + (size_t)(t & 1) * (8 * Bn);
            ull* s2 = w.lbs + (size_t)(t & 1) * (8 * Bn);
            #pragma unroll
            for (int s = 0; s < 8; ++s) { stA(&s1[s * Bn + b], 0ull); stA(&s2[s * Bn + b], 0ull); }
        }
    }
    __syncthreads();
    if (t >= T) return;

    if (tid < 768) {
        int d = tid >> 2, q = tid & 3;
        int b = d & 31, rem = d >> 5, gate = rem >> 1, ci = rem & 1;
        int col = bid + (ci << 8);
        const float* wrow = W_ih + (size_t)(gate * Hn + col) * En + q * (En / 4);
        const float* xrow = emb + (size_t)sm->tok[b] * En + q * (En / 4);
        float ax = 0.f, ay = 0.f;
        #pragma unroll
        for (int e4 = 0; e4 < En / 16; ++e4) {
            float4 w4 = *(const float4*)(wrow + 4 * e4);
            float4 x4 = *(const float4*)(xrow + 4 * e4);
            ax = fmaf(x4.x, w4.x, ax); ay = fmaf(x4.y, w4.y, ay);
            ax = fmaf(x4.z, w4.z, ax); ay = fmaf(x4.w, w4.w, ay);
        }
        float a = ax + ay;
        a += __shfl_xor(a, 1);
        a += __shfl_xor(a, 2);
        if (q == 0) sm->gx[(ci * 3 + gate) * 32 + b] = a;
    }
    __syncthreads();

    if (tid < 64) {
        int b = tid & 31, ci = tid >> 5;
        int col = col_a;
        float gxr = sm->gx[(ci * 3 + 0) * 32 + b] + b_ih[col];
        float gxz = sm->gx[(ci * 3 + 1) * 32 + b] + b_ih[Hn + col];
        float gxn = sm->gx[(ci * 3 + 2) * 32 + b] + b_ih[2 * Hn + col];
        float r = 1.0f / (1.0f + expf(-(gxr + ghr)));
        float z = 1.0f / (1.0f + expf(-(gxz + ghz)));
        float n = tanhf(gxn + r * ghn);
        float* hp = w.h + (size_t)b * Hn + col;
        float hold = ldA(hp);
        stA(hp, (1.0f - z) * n + z * hold);
    }
}

// ================= cooperative single-kernel path =================
__global__ void __launch_bounds__(NTHR, 4)
decode_coop(const float* __restrict__ hidden, const float* __restrict__ emb,
            const float* __restrict__ W_ih, const float* __restrict__ W_hh,
            const float* __restrict__ b_ih, const float* __restrict__ b_hh,
            const float* __restrict__ W_proj, const float* __restrict__ b_proj,
            const int* __restrict__ max_len_p, int* __restrict__ out, void* ws_raw)
{
    const int tid = threadIdx.x, bid = blockIdx.x;
    __shared__ SM sm;
    WS w = get_ws(ws_raw);
    const int T = max_len_p[0];

    prologue(tid, bid, hidden, W_proj, w);
    grid_barrier(bid);
    stage_h(tid, w, &sm);                            // gh(h0) via LDS
    __syncthreads();
    do_gh(tid, bid, W_hh, &sm);
    __syncthreads();
    fin_gh(tid, 0, bid, b_hh, w.gh, &sm);
    grid_barrier(bid);

    for (int t = 0; t < T; ++t) {
        phase_a(tid, bid, t, T, emb, W_ih, b_ih, w, out, &sm);
        grid_barrier(bid);
        phase_bc(tid, bid, t, w, W_hh, b_hh, W_proj, b_proj, &sm);
        grid_barrier(bid);
    }
    phase_a(tid, bid, T, T, emb, W_ih, b_ih, w, out, &sm);
}

// ================= non-cooperative fallback path =================
__global__ void __launch_bounds__(NTHR, 4)
k_pro(const float* __restrict__ hidden, const float* __restrict__ W_proj, void* ws_raw) {
    WS w = get_ws(ws_raw);
    prologue(threadIdx.x, blockIdx.x, hidden, W_proj, w);
}
__global__ void __launch_bounds__(NTHR, 4)
k_pre(const float* __restrict__ W_hh, const float* __restrict__ b_hh, void* ws_raw) {
    __shared__ SM sm;
    WS w = get_ws(ws_raw);
    stage_h(threadIdx.x, w, &sm);
    __syncthreads();
    do_gh(threadIdx.x, blockIdx.x, W_hh, &sm);
    __syncthreads();
    fin_gh(threadIdx.x, 0, blockIdx.x, b_hh, w.gh, &sm);
}
__global__ void __launch_bounds__(NTHR, 4)
k_a(int t, const int* __restrict__ max_len_p,
    const float* __restrict__ emb, const float* __restrict__ W_ih,
    const float* __restrict__ b_ih, int* __restrict__ out, void* ws_raw)
{
    int T = max_len_p[0];
    if (t > T) return;
    __shared__ SM sm;
    WS w = get_ws(ws_raw);
    phase_a(threadIdx.x, blockIdx.x, t, T, emb, W_ih, b_ih, w, out, &sm);
}
__global__ void __launch_bounds__(NTHR, 4)
k_bc(int t, const int* __restrict__ max_len_p,
     const float* __restrict__ W_hh, const float* __restrict__ b_hh,
     const float* __restrict__ W_proj, const float* __restrict__ b_proj, void* ws_raw)
{
    if (t >= max_len_p[0]) return;
    __shared__ SM sm;
    WS w = get_ws(ws_raw);
    phase_bc(threadIdx.x, blockIdx.x, t, w, W_hh, b_hh, W_proj, b_proj, &sm);
}

extern "C" void kernel_launch(void* const* d_in, const int* in_sizes, int n_in,
                              void* d_out, int out_size, void* d_ws, size_t ws_size,
                              hipStream_t stream) {
    const float* hidden = (const float*)d_in[0];
    const float* emb    = (const float*)d_in[1];
    const float* W_ih   = (const float*)d_in[2];
    const float* W_hh   = (const float*)d_in[3];
    const float* b_ih   = (const float*)d_in[4];
    const float* b_hh   = (const float*)d_in[5];
    const float* W_proj = (const float*)d_in[6];
    const float* b_proj = (const float*)d_in[7];
    const int* max_len  = (const int*)d_in[8];
    int* out = (int*)d_out;
    void* ws = d_ws;

    void* args[] = {&hidden, &emb, &W_ih, &W_hh, &b_ih, &b_hh,
                    &W_proj, &b_proj, &max_len, &out, &ws};
    hipError_t err = hipLaunchCooperativeKernel((const void*)decode_coop,
                                                dim3(NBLK), dim3(NTHR), args, 0, stream);
    if (err != hipSuccess) {
        (void)hipGetLastError();   // deterministic fallback chain
        hipLaunchKernelGGL(k_pro, dim3(NBLK), dim3(NTHR), 0, stream, hidden, W_proj, ws);
        hipLaunchKernelGGL(k_pre, dim3(NBLK), dim3(NTHR), 0, stream, W_hh, b_hh, ws);
        for (int t = 0; t <= 64; ++t) {
            hipLaunchKernelGGL(k_a, dim3(NBLK), dim3(NTHR), 0, stream,
                               t, max_len, emb, W_ih, b_ih, out, ws);
            if (t < 64) {
                hipLaunchKernelGGL(k_bc, dim3(NBLK), dim3(NTHR), 0, stream,
                                   t, max_len, W_hh, b_hh, W_proj, b_proj, ws);
            }
        }
    }
}